// Round 9
// baseline (228.604 us; speedup 1.0000x reference)
//
#include <hip/hip_runtime.h>
#include <hip/hip_bf16.h>

typedef __hip_bfloat16 bf16;
typedef __attribute__((ext_vector_type(8))) short short8;
typedef __attribute__((ext_vector_type(4))) float f32x4;

#define S  3
#define V  25
#define C  64
#define O  64
#define IC 16
#define NN 32
#define TT 256
#define TB 2
#define TCH 4

__device__ __forceinline__ float b2f(bf16 v) { return __bfloat162float(v); }

__device__ __forceinline__ float ldv(const void* p, size_t i, int f32) {
    return f32 ? ((const float*)p)[i] : b2f(((const bf16*)p)[i]);
}

__device__ __forceinline__ unsigned short f2bf(float f) {
    bf16 h = __float2bfloat16(f);
    return *(unsigned short*)&h;
}

// ---------------------------------------------------------------------------
// k_prep: dtype sniff; zero S1; weights -> bf16 MFMA layouts; A_comb.
// ---------------------------------------------------------------------------
__global__ __launch_bounds__(256) void k_prep(
    const void* __restrict__ x,
    const void* __restrict__ A, const void* __restrict__ PA,
    const void* __restrict__ wA,
    const void* __restrict__ Wa, const void* __restrict__ Wb,
    const void* __restrict__ Wd,
    float* __restrict__ A_comb, float* __restrict__ S1,
    unsigned short* __restrict__ wprep, int* __restrict__ flagp) {
    __shared__ int sflag;
    if (threadIdx.x < 64) {
        const bf16* p = (const bf16*)x;
        int bad = 0;
        #pragma unroll
        for (int k = 0; k < 32; k++) {
            float v = b2f(p[threadIdx.x + k * 64]);
            bad |= !(v > -1000.f && v < 1000.f);
        }
        unsigned long long m = __ballot(bad);
        if (threadIdx.x == 0) {
            sflag = (m != 0ull) ? 1 : 0;
            if (blockIdx.x == 0) *flagp = sflag;
        }
    }
    __syncthreads();
    int f32 = sflag;

    int g = blockIdx.x * 256 + threadIdx.x;
    int stride = gridDim.x * 256;

    for (int w = g; w < 60000; w += stride) S1[w] = 0.f;

    for (int w = g; w < 3456; w += stride) {           // Wa/Wb -> [i][c] bf16
        int s = w / 1152, r = w % 1152, i = r / 72, c = r % 72;
        unsigned short va = 0, vb = 0;
        if (c < 64) {
            va = f2bf(ldv(Wa, (size_t)s * 1024 + c * 16 + i, f32));
            vb = f2bf(ldv(Wb, (size_t)s * 1024 + c * 16 + i, f32));
        }
        wprep[s * 6912 + i * 72 + c] = va;
        wprep[s * 6912 + 1152 + i * 72 + c] = vb;
    }
    for (int w = g; w < 13824; w += stride) {          // Wd -> [o][c] bf16
        int s = w / 4608, r = w % 4608, o = r / 72, c = r % 72;
        unsigned short vd = 0;
        if (c < 64) vd = f2bf(ldv(Wd, (size_t)s * 4096 + c * 64 + o, f32));
        wprep[s * 6912 + 2304 + o * 72 + c] = vd;
    }

    if (g < S * V) {                                    // A_comb rows
        float w0 = ldv(wA, 0, f32), w1 = ldv(wA, 1, f32);
        float vals[V];
        float m = -1e30f;
        for (int v = 0; v < V; v++) { vals[v] = ldv(PA, g * V + v, f32); m = fmaxf(m, vals[v]); }
        float sum = 0.f;
        for (int v = 0; v < V; v++) { vals[v] = __expf(vals[v] - m); sum += vals[v]; }
        float inv = 1.f / sum;
        for (int v = 0; v < V; v++)
            A_comb[g * V + v] = w0 * ldv(A, g * V + v, f32) + w1 * vals[v] * inv;
    }
}

// ---------------------------------------------------------------------------
// k_s1 round-9: TCH 8->4 (grid 2048). Round-8's grid of 1024 blocks under-
// filled the 6-blocks/CU x 256 CU = 1536 resident capacity (one partial
// generation, no block-level pipelining). 2048 blocks fill all slots with
// turnover; per-block barriers 8->5. Weights direct from L2-hot wprep.
// ---------------------------------------------------------------------------
#define P1_QK(sidx, QB, KB) do {                                              \
    const unsigned short* wat_ = wprep + (size_t)(sidx) * 6912;               \
    const unsigned short* wbt_ = wat_ + 1152;                                 \
    short8 wa0 = *(const short8*)&wat_[lm * 72 + kq * 8];                     \
    short8 wa1 = *(const short8*)&wat_[lm * 72 + 32 + kq * 8];                \
    short8 wb0 = *(const short8*)&wbt_[lm * 72 + kq * 8];                     \
    short8 wb1 = *(const short8*)&wbt_[lm * 72 + 32 + kq * 8];                \
    f32x4 q = __builtin_amdgcn_mfma_f32_16x16x32_bf16(xa0, wa0, (f32x4){0.f,0.f,0.f,0.f}, 0, 0, 0); \
    q = __builtin_amdgcn_mfma_f32_16x16x32_bf16(xa1, wa1, q, 0, 0, 0);        \
    f32x4 k = __builtin_amdgcn_mfma_f32_16x16x32_bf16(xa0, wb0, (f32x4){0.f,0.f,0.f,0.f}, 0, 0, 0); \
    k = __builtin_amdgcn_mfma_f32_16x16x32_bf16(xa1, wb1, k, 0, 0, 0);        \
    _Pragma("unroll")                                                         \
    for (int reg = 0; reg < 4; reg++) {                                       \
        (QB)[(drow0 + reg) * 20 + lm] = f2bf(q[reg] + rbq[sidx]);             \
        (KB)[(drow0 + reg) * 20 + lm] = f2bf(k[reg] + rbk[sidx]);             \
    }                                                                         \
} while (0)

#define E_ACC(AC, QB, KB) do {                                                \
    short8 a_ = *(const short8*)&(QB)[(tsel + ur0 + lm) * 20 + ksel];         \
    short8 b_ = *(const short8*)&(KB)[(tsel + vc0 + lm) * 20 + ksel];         \
    (AC) = __builtin_amdgcn_mfma_f32_16x16x32_bf16(a_, b_, (AC), 0, 0, 0);    \
} while (0)

#define STAGE_XB(TTOFF) do {                                                  \
    if (f32) {                                                                \
        const float4* xp = (const float4*)x + (size_t)(n * TT + t0 + (TTOFF)) * 400; \
        for (int w = tid; w < 800; w += 256) {                                \
            int t = w / 400, r = w % 400, u = r >> 4, c4 = r & 15;            \
            float4 v = xp[w];                                                 \
            unsigned short h[4] = {f2bf(v.x), f2bf(v.y), f2bf(v.z), f2bf(v.w)}; \
            *(uint2*)&xb[(t * 32 + u) * 72 + c4 * 4] = *(uint2*)h;            \
        }                                                                     \
    } else {                                                                  \
        const unsigned int* xp = (const unsigned int*)x;                      \
        size_t base2 = (size_t)(n * TT + t0 + (TTOFF)) * V * C / 2;           \
        for (int w = tid; w < 1600; w += 256) {                               \
            int t = w / 800, r = w % 800, u = r >> 5, c2 = r & 31;            \
            ((unsigned int*)xb)[(t * 32 + u) * 36 + c2] = xp[base2 + (size_t)(t * V + u) * 32 + c2]; \
        }                                                                     \
    }                                                                         \
} while (0)

__global__ __launch_bounds__(256) void k_s1(
    const void* __restrict__ x,
    const unsigned short* __restrict__ wprep,
    const void* __restrict__ ba, const void* __restrict__ bb,
    float* __restrict__ S1g, const int* __restrict__ flagp) {
    int f32 = *flagp;
    int tchunk = blockIdx.x, n = blockIdx.y;
    int tid = threadIdx.x;
    int lane = tid & 63, wv = tid >> 6;
    int lm = lane & 15, kq = lane >> 4;

    __shared__ __align__(16) unsigned short xb[64 * 72];       // 9216 B
    __shared__ __align__(16) unsigned short qb[3][64 * 20];    // 7680 B
    __shared__ __align__(16) unsigned short kb_[3][64 * 20];   // 7680 B
    // total 24576 B -> 6 blocks/CU

    float rbq[3], rbk[3];
    #pragma unroll
    for (int s = 0; s < 3; s++) {
        rbq[s] = ldv(ba, s * IC + lm, f32);
        rbk[s] = ldv(bb, s * IC + lm, f32);
    }

    int mrow = wv * 16 + lm;
    int drow0 = wv * 16 + (kq << 2);
    int ur0 = ((wv >> 1) & 1) << 4;   // wave quadrant rows
    int vc0 = (wv & 1) << 4;          //               cols
    int t0 = tchunk * TCH;
    int tsel = (kq >> 1) << 5;        // E-frag: k<16 -> t0 rows, k>=16 -> t1
    int ksel = (kq & 1) << 3;

    f32x4 acc0 = {0.f,0.f,0.f,0.f}, acc1 = {0.f,0.f,0.f,0.f}, acc2 = {0.f,0.f,0.f,0.f};

    STAGE_XB(0);
    __syncthreads();

    for (int pp = 0; pp < TCH / 2; pp++) {
        short8 xa0 = *(const short8*)&xb[mrow * 72 + kq * 8];
        short8 xa1 = *(const short8*)&xb[mrow * 72 + 32 + kq * 8];
        P1_QK(0, qb[0], kb_[0]);
        P1_QK(1, qb[1], kb_[1]);
        P1_QK(2, qb[2], kb_[2]);
        __syncthreads();                 // all P1 writes visible; xb reads done
        E_ACC(acc0, qb[0], kb_[0]);
        E_ACC(acc1, qb[1], kb_[1]);
        E_ACC(acc2, qb[2], kb_[2]);
        if (pp < TCH / 2 - 1) STAGE_XB(2 * pp + 2);   // overlaps with E MFMAs
        __syncthreads();                 // xb ready; E reads done before next P1
    }

    // ---- reduce into S1 (C-layout: row = kq*4+reg, col = lm, + quadrant)
    {
        int u = ur0 + (kq << 2), v = vc0 + lm;
        float* d0 = S1g + (size_t)n * 625;
        float* d1 = S1g + ((size_t)NN + n) * 625;
        float* d2 = S1g + ((size_t)2 * NN + n) * 625;
        #pragma unroll
        for (int reg = 0; reg < 4; reg++) {
            if (u + reg < V && v < V) {
                atomicAdd(&d0[(u + reg) * 25 + v], acc0[reg]);
                atomicAdd(&d1[(u + reg) * 25 + v], acc1[reg]);
                atomicAdd(&d2[(u + reg) * 25 + v], acc2[reg]);
            }
        }
    }
}

// ---------------------------------------------------------------------------
// k_a1: in place S1 row <- A_comb + w2 * softmax(S1row / 64)   (= ac1)
// ---------------------------------------------------------------------------
__global__ void k_a1(float* __restrict__ S1g, const float* __restrict__ A_comb,
                     const void* __restrict__ wA, const int* __restrict__ flagp) {
    int f32 = *flagp;
    float w2 = ldv(wA, 2, f32);
    int sn = blockIdx.x;
    int s = sn / NN;
    int u = threadIdx.x;
    if (u >= V) return;
    float* row = S1g + (size_t)sn * V * V + u * V;
    const float* ac = A_comb + (size_t)(s * V + u) * V;
    const float scale = 1.0f / 64.0f;
    float vals[V];
    float m = -1e30f;
    for (int v = 0; v < V; v++) { vals[v] = row[v] * scale; m = fmaxf(m, vals[v]); }
    float sum = 0.f;
    for (int v = 0; v < V; v++) { vals[v] = __expf(vals[v] - m); sum += vals[v]; }
    float inv = w2 / sum;
    for (int v = 0; v < V; v++) row[v] = ac[v] + vals[v] * inv;
}

// ---------------------------------------------------------------------------
// k_main (round-8 structure; only change: deleted the dead col-pad zero loop
// — cols 64-71 of real rows are never read by xa fragments (<=63), epilogue
// (o<=63), or P3): direct-global weight fragments, in-place qab/A_in,
// 2 barriers per s-iter, staged coalesced epilogue.
// ---------------------------------------------------------------------------
__global__ __launch_bounds__(256, 5) void k_main(
    const void* __restrict__ x,
    const void* __restrict__ ba, const void* __restrict__ bb,
    const void* __restrict__ bd,
    const void* __restrict__ gamma, const void* __restrict__ beta,
    const void* __restrict__ wA,
    const unsigned short* __restrict__ wprep,
    const float* __restrict__ ac1g,
    void* __restrict__ outp, const int* __restrict__ flagp) {
    int f32 = *flagp;
    int bx = blockIdx.x;
    int n = bx >> 7, tc = bx & 127;
    int t0 = tc * TB;
    int tid = threadIdx.x;
    int lane = tid & 63, wv = tid >> 6;
    int lm = lane & 15, kq = lane >> 4;

    __shared__ __align__(16) unsigned short xb[64 * 72];       // 9216 B
    __shared__ __align__(16) unsigned short qab[64 * 40];      // 5120 B (q | later A_in)
    __shared__ __align__(16) unsigned short kbb[64 * 40];      // 5120 B
    __shared__ __align__(16) unsigned short xwtb[2 * 64 * 40]; // 10240 B (later epilogue stage)
    __shared__ float gs[O], bts[O], bds[O];                    // 768 B

    // ---- stage xb (bf16, rows t*32+u, stride 72)
    if (f32) {
        const float4* xp = (const float4*)x + (size_t)(n * TT + t0) * 400;
        for (int w = tid; w < 800; w += 256) {
            int t = w / 400, r = w % 400, u = r >> 4, c4 = r & 15;
            float4 v = xp[w];
            unsigned short h[4] = {f2bf(v.x), f2bf(v.y), f2bf(v.z), f2bf(v.w)};
            *(uint2*)&xb[(t * 32 + u) * 72 + c4 * 4] = *(uint2*)h;
        }
    } else {
        const unsigned int* xp = (const unsigned int*)x;
        size_t base2 = (size_t)(n * TT + t0) * V * C / 2;
        for (int w = tid; w < 1600; w += 256) {
            int t = w / 800, r = w % 800, u = r >> 5, c2 = r & 31;
            ((unsigned int*)xb)[(t * 32 + u) * 36 + c2] = xp[base2 + (size_t)(t * V + u) * 32 + c2];
        }
    }
    // zero ghost rows u=25..31 (both t)
    for (int w = tid; w < 14 * 36; w += 256) {
        int idx = w / 36, word = w % 36;
        int row = (idx < 7) ? (25 + idx) : (32 + 25 + idx - 7);
        ((unsigned int*)xb)[row * 36 + word] = 0;
    }
    // zero qab/kbb k-pad cols 16..31 (kbb: permanent; qab: refreshed by P4)
    for (int w = tid; w < 512; w += 256) {
        int r = w >> 3, cw = 8 + (w & 7);
        ((unsigned int*)qab)[r * 20 + cw] = 0;
        ((unsigned int*)kbb)[r * 20 + cw] = 0;
    }
    if (tid < O) {
        bds[tid] = ldv(bd, tid, f32) + ldv(bd, O + tid, f32) + ldv(bd, 2 * O + tid, f32);
        gs[tid] = ldv(gamma, tid, f32) * rsqrtf(1.f + 1e-5f);
        bts[tid] = ldv(beta, tid, f32);
    }
    float w3 = ldv(wA, 3, f32);

    f32x4 acc[4];
    #pragma unroll
    for (int nt = 0; nt < 4; nt++) acc[nt] = (f32x4){0.f, 0.f, 0.f, 0.f};

    int t_ = wv >> 1;
    int mrow = wv * 16 + lm;
    int drow0 = wv * 16 + (kq << 2);
    int ub = ((wv & 1) << 4) + (kq << 2);

    __syncthreads();   // xb / pads / gs ready

    // x fragments are loop-invariant: hoist
    short8 xa0 = *(const short8*)&xb[mrow * 72 + kq * 8];
    short8 xa1 = *(const short8*)&xb[mrow * 72 + 32 + kq * 8];

    for (int s = 0; s < S; s++) {
        const unsigned short* watg = wprep + s * 6912;
        const unsigned short* wbtg = watg + 1152;
        const unsigned short* wdtg = watg + 2304;
        const float* acn = ac1g + ((size_t)s * NN + n) * 625;

        // ---- P1: qa/kb MFMA (weights direct from L2-hot global)
        {
            short8 wa0 = *(const short8*)&watg[lm * 72 + kq * 8];
            short8 wa1 = *(const short8*)&watg[lm * 72 + 32 + kq * 8];
            short8 wb0 = *(const short8*)&wbtg[lm * 72 + kq * 8];
            short8 wb1 = *(const short8*)&wbtg[lm * 72 + 32 + kq * 8];
            float bq_c = ldv(ba, s * IC + lm, f32);
            float bk_c = ldv(bb, s * IC + lm, f32);
            f32x4 q = __builtin_amdgcn_mfma_f32_16x16x32_bf16(xa0, wa0, (f32x4){0.f,0.f,0.f,0.f}, 0, 0, 0);
            q = __builtin_amdgcn_mfma_f32_16x16x32_bf16(xa1, wa1, q, 0, 0, 0);
            f32x4 k = __builtin_amdgcn_mfma_f32_16x16x32_bf16(xa0, wb0, (f32x4){0.f,0.f,0.f,0.f}, 0, 0, 0);
            k = __builtin_amdgcn_mfma_f32_16x16x32_bf16(xa1, wb1, k, 0, 0, 0);
            #pragma unroll
            for (int reg = 0; reg < 4; reg++) {
                qab[(drow0 + reg) * 40 + lm] = f2bf(q[reg] + bq_c);
                kbb[(drow0 + reg) * 40 + lm] = f2bf(k[reg] + bk_c);
            }
        }
        // ---- P3: xw = xb * Wd -> xwtb transposed [t][o][v]
        {
            #pragma unroll
            for (int nt = 0; nt < 4; nt++) {
                short8 wd0 = *(const short8*)&wdtg[(nt * 16 + lm) * 72 + kq * 8];
                short8 wd1 = *(const short8*)&wdtg[(nt * 16 + lm) * 72 + 32 + kq * 8];
                f32x4 xw = __builtin_amdgcn_mfma_f32_16x16x32_bf16(xa0, wd0, (f32x4){0.f,0.f,0.f,0.f}, 0, 0, 0);
                xw = __builtin_amdgcn_mfma_f32_16x16x32_bf16(xa1, wd1, xw, 0, 0, 0);
                unsigned short h[4] = {f2bf(xw[0]), f2bf(xw[1]), f2bf(xw[2]), f2bf(xw[3])};
                *(uint2*)&xwtb[t_ * 2560 + (nt * 16 + lm) * 40 + ub] = *(uint2*)h;
            }
        }
        __syncthreads();   // sync_A: kbb (P1->P2, cross-wave), xwtb (P3->P4, cross-wave)

        // ---- P2: E MFMA -> exp -> rowsum(shfl) -> combine -> A_in (into qab, in place)
        {
            short8 aq = *(const short8*)&qab[mrow * 40 + kq * 8];
            short8 bk0 = *(const short8*)&kbb[(t_ * 32 + lm) * 40 + kq * 8];
            short8 bk1 = *(const short8*)&kbb[(t_ * 32 + 16 + lm) * 40 + kq * 8];
            f32x4 e0 = __builtin_amdgcn_mfma_f32_16x16x32_bf16(aq, bk0, (f32x4){0.f,0.f,0.f,0.f}, 0, 0, 0);
            f32x4 e1 = __builtin_amdgcn_mfma_f32_16x16x32_bf16(aq, bk1, (f32x4){0.f,0.f,0.f,0.f}, 0, 0, 0);
            #pragma unroll
            for (int reg = 0; reg < 4; reg++) {
                float p0 = __expf(e0[reg] * 0.25f);
                float p1 = (lm < V - 16) ? __expf(e1[reg] * 0.25f) : 0.f;
                float pr = p0 + p1;
                pr += __shfl_xor(pr, 1);
                pr += __shfl_xor(pr, 2);
                pr += __shfl_xor(pr, 4);
                pr += __shfl_xor(pr, 8);
                float si = w3 / pr;
                int u = ub + reg;
                int uc = (u < V) ? u : 0;
                float a0v = (u < V) ? (acn[uc * 25 + lm] + si * p0) : 0.f;
                float a1v = (u < V && lm < V - 16) ? (acn[uc * 25 + 16 + lm] + si * p1) : 0.f;
                qab[(drow0 + reg) * 40 + lm] = f2bf(a0v);
                qab[(drow0 + reg) * 40 + 16 + lm] = f2bf(a1v);
            }
        }
        // ---- P4: y += A_in * xwtb  (no barrier needed: qab rows wave-private,
        //      xwtb written pre-sync_A)
        {
            short8 aA = *(const short8*)&qab[mrow * 40 + kq * 8];
            #pragma unroll
            for (int nt = 0; nt < 4; nt++) {
                short8 bx8 = *(const short8*)&xwtb[t_ * 2560 + (nt * 16 + lm) * 40 + kq * 8];
                acc[nt] = __builtin_amdgcn_mfma_f32_16x16x32_bf16(aA, bx8, acc[nt], 0, 0, 0);
            }
            // restore qab K-pad zeros for next s's aq read (wave-private rows)
            if (s < S - 1) {
                #pragma unroll
                for (int reg = 0; reg < 4; reg++)
                    qab[(drow0 + reg) * 40 + 16 + lm] = 0;
            }
        }
        __syncthreads();   // sync_B: next-iter P1/P3 overwrite kbb/xwtb
    }

    // ---- epilogue: BN + residual + relu
    if (f32) {
        #pragma unroll
        for (int nt = 0; nt < 4; nt++) {
            int o = nt * 16 + lm;
            float g = gs[o], bt_ = bts[o], bsum = bds[o];
            #pragma unroll
            for (int reg = 0; reg < 4; reg++) {
                int grow = drow0 + reg;
                int t = grow >> 5, u = grow & 31;
                if (u < V) {
                    float xres = b2f(*(const bf16*)&xb[grow * 72 + o]);
                    float yv = fmaxf((acc[nt][reg] + bsum) * g + bt_ + xres, 0.f);
                    size_t ob = (size_t)((n * TT + t0 + t) * V + u) * O + o;
                    ((float*)outp)[ob] = yv;
                }
            }
        }
    } else {
        // stage bf16 results in xwtb (free after last P4 + sync_B), then dump
        // the block's contiguous 6400B output with coalesced 16B stores.
        unsigned short* ep = xwtb;
        #pragma unroll
        for (int nt = 0; nt < 4; nt++) {
            int o = nt * 16 + lm;
            float g = gs[o], bt_ = bts[o], bsum = bds[o];
            #pragma unroll
            for (int reg = 0; reg < 4; reg++) {
                int grow = drow0 + reg;
                int t = grow >> 5, u = grow & 31;
                if (u < V) {
                    float xres = b2f(*(const bf16*)&xb[grow * 72 + o]);
                    float yv = fmaxf((acc[nt][reg] + bsum) * g + bt_ + xres, 0.f);
                    ep[(t * V + u) * O + o] = f2bf(yv);
                }
            }
        }
        __syncthreads();
        uint4* outv = (uint4*)((bf16*)outp + (size_t)(n * TT + t0) * V * O);
        const uint4* epv = (const uint4*)ep;
        for (int w = tid; w < 400; w += 256) outv[w] = epv[w];
    }
}

// ---------------------------------------------------------------------------
extern "C" void kernel_launch(void* const* d_in, const int* in_sizes, int n_in,
                              void* d_out, int out_size, void* d_ws, size_t ws_size,
                              hipStream_t stream) {
    const void* x     = d_in[0];
    const void* A     = d_in[1];
    const void* PA    = d_in[2];
    const void* wA    = d_in[3];
    const void* Wa    = d_in[4];
    const void* ba    = d_in[5];
    const void* Wb    = d_in[6];
    const void* bb    = d_in[7];
    const void* Wd    = d_in[8];
    const void* bd    = d_in[9];
    const void* gamma = d_in[10];
    const void* beta  = d_in[11];

    int*   flagp  = (int*)d_ws;
    float* wsf    = (float*)d_ws;
    float* A_comb = wsf + 64;                         // 1875 f
    float* S1     = wsf + 2048;                       // 60000 f (becomes ac1)
    unsigned short* wprep = (unsigned short*)(wsf + 65536);  // 20736 sh

    k_prep<<<64, 256, 0, stream>>>(x, A, PA, wA, Wa, Wb, Wd, A_comb, S1, wprep, flagp);
    k_s1<<<dim3(TT / TCH, NN), 256, 0, stream>>>(x, wprep, ba, bb, S1, flagp);
    k_a1<<<S * NN, 64, 0, stream>>>(S1, A_comb, wA, flagp);
    k_main<<<NN * TT / TB, 256, 0, stream>>>(x, ba, bb, bd, gamma, beta, wA,
                                             wprep, S1, d_out, flagp);
}

// Round 10
// 212.476 us; speedup vs baseline: 1.0759x; 1.0759x over previous
//
#include <hip/hip_runtime.h>
#include <hip/hip_bf16.h>

typedef __hip_bfloat16 bf16;
typedef __attribute__((ext_vector_type(8))) short short8;
typedef __attribute__((ext_vector_type(4))) float f32x4;

#define S  3
#define V  25
#define C  64
#define O  64
#define IC 16
#define NN 32
#define TT 256
#define TB 2
#define TCH 8

__device__ __forceinline__ float b2f(bf16 v) { return __bfloat162float(v); }

__device__ __forceinline__ float ldv(const void* p, size_t i, int f32) {
    return f32 ? ((const float*)p)[i] : b2f(((const bf16*)p)[i]);
}

__device__ __forceinline__ unsigned short f2bf(float f) {
    bf16 h = __float2bfloat16(f);
    return *(unsigned short*)&h;
}

// ---------------------------------------------------------------------------
// k_prep: dtype sniff; zero S1; weights -> bf16 MFMA layouts; A_comb.
// round-10: grid 64->256 blocks (more TLP for the strided transpose loads).
// ---------------------------------------------------------------------------
__global__ __launch_bounds__(256) void k_prep(
    const void* __restrict__ x,
    const void* __restrict__ A, const void* __restrict__ PA,
    const void* __restrict__ wA,
    const void* __restrict__ Wa, const void* __restrict__ Wb,
    const void* __restrict__ Wd,
    float* __restrict__ A_comb, float* __restrict__ S1,
    unsigned short* __restrict__ wprep, int* __restrict__ flagp) {
    __shared__ int sflag;
    if (threadIdx.x < 64) {
        const bf16* p = (const bf16*)x;
        int bad = 0;
        #pragma unroll
        for (int k = 0; k < 32; k++) {
            float v = b2f(p[threadIdx.x + k * 64]);
            bad |= !(v > -1000.f && v < 1000.f);
        }
        unsigned long long m = __ballot(bad);
        if (threadIdx.x == 0) {
            sflag = (m != 0ull) ? 1 : 0;
            if (blockIdx.x == 0) *flagp = sflag;
        }
    }
    __syncthreads();
    int f32 = sflag;

    int g = blockIdx.x * 256 + threadIdx.x;
    int stride = gridDim.x * 256;

    for (int w = g; w < 60000; w += stride) S1[w] = 0.f;

    for (int w = g; w < 3456; w += stride) {           // Wa/Wb -> [i][c] bf16
        int s = w / 1152, r = w % 1152, i = r / 72, c = r % 72;
        unsigned short va = 0, vb = 0;
        if (c < 64) {
            va = f2bf(ldv(Wa, (size_t)s * 1024 + c * 16 + i, f32));
            vb = f2bf(ldv(Wb, (size_t)s * 1024 + c * 16 + i, f32));
        }
        wprep[s * 6912 + i * 72 + c] = va;
        wprep[s * 6912 + 1152 + i * 72 + c] = vb;
    }
    for (int w = g; w < 13824; w += stride) {          // Wd -> [o][c] bf16
        int s = w / 4608, r = w % 4608, o = r / 72, c = r % 72;
        unsigned short vd = 0;
        if (c < 64) vd = f2bf(ldv(Wd, (size_t)s * 4096 + c * 64 + o, f32));
        wprep[s * 6912 + 2304 + o * 72 + c] = vd;
    }

    if (g < S * V) {                                    // A_comb rows
        float w0 = ldv(wA, 0, f32), w1 = ldv(wA, 1, f32);
        float vals[V];
        float m = -1e30f;
        for (int v = 0; v < V; v++) { vals[v] = ldv(PA, g * V + v, f32); m = fmaxf(m, vals[v]); }
        float sum = 0.f;
        for (int v = 0; v < V; v++) { vals[v] = __expf(vals[v] - m); sum += vals[v]; }
        float inv = 1.f / sum;
        for (int v = 0; v < V; v++)
            A_comb[g * V + v] = w0 * ldv(A, g * V + v, f32) + w1 * vals[v] * inv;
    }
}

// ---------------------------------------------------------------------------
// k_s1 (round-8 exact, the best-measured config): TCH=8, grid 1024 blocks,
// 6 blocks/CU; 2 barriers per t-pair; weights direct from L2-hot wprep.
// ---------------------------------------------------------------------------
#define P1_QK(sidx, QB, KB) do {                                              \
    const unsigned short* wat_ = wprep + (size_t)(sidx) * 6912;               \
    const unsigned short* wbt_ = wat_ + 1152;                                 \
    short8 wa0 = *(const short8*)&wat_[lm * 72 + kq * 8];                     \
    short8 wa1 = *(const short8*)&wat_[lm * 72 + 32 + kq * 8];                \
    short8 wb0 = *(const short8*)&wbt_[lm * 72 + kq * 8];                     \
    short8 wb1 = *(const short8*)&wbt_[lm * 72 + 32 + kq * 8];                \
    f32x4 q = __builtin_amdgcn_mfma_f32_16x16x32_bf16(xa0, wa0, (f32x4){0.f,0.f,0.f,0.f}, 0, 0, 0); \
    q = __builtin_amdgcn_mfma_f32_16x16x32_bf16(xa1, wa1, q, 0, 0, 0);        \
    f32x4 k = __builtin_amdgcn_mfma_f32_16x16x32_bf16(xa0, wb0, (f32x4){0.f,0.f,0.f,0.f}, 0, 0, 0); \
    k = __builtin_amdgcn_mfma_f32_16x16x32_bf16(xa1, wb1, k, 0, 0, 0);        \
    _Pragma("unroll")                                                         \
    for (int reg = 0; reg < 4; reg++) {                                       \
        (QB)[(drow0 + reg) * 20 + lm] = f2bf(q[reg] + rbq[sidx]);             \
        (KB)[(drow0 + reg) * 20 + lm] = f2bf(k[reg] + rbk[sidx]);             \
    }                                                                         \
} while (0)

#define E_ACC(AC, QB, KB) do {                                                \
    short8 a_ = *(const short8*)&(QB)[(tsel + ur0 + lm) * 20 + ksel];         \
    short8 b_ = *(const short8*)&(KB)[(tsel + vc0 + lm) * 20 + ksel];         \
    (AC) = __builtin_amdgcn_mfma_f32_16x16x32_bf16(a_, b_, (AC), 0, 0, 0);    \
} while (0)

#define STAGE_XB(TTOFF) do {                                                  \
    if (f32) {                                                                \
        const float4* xp = (const float4*)x + (size_t)(n * TT + t0 + (TTOFF)) * 400; \
        for (int w = tid; w < 800; w += 256) {                                \
            int t = w / 400, r = w % 400, u = r >> 4, c4 = r & 15;            \
            float4 v = xp[w];                                                 \
            unsigned short h[4] = {f2bf(v.x), f2bf(v.y), f2bf(v.z), f2bf(v.w)}; \
            *(uint2*)&xb[(t * 32 + u) * 72 + c4 * 4] = *(uint2*)h;            \
        }                                                                     \
    } else {                                                                  \
        const unsigned int* xp = (const unsigned int*)x;                      \
        size_t base2 = (size_t)(n * TT + t0 + (TTOFF)) * V * C / 2;           \
        for (int w = tid; w < 1600; w += 256) {                               \
            int t = w / 800, r = w % 800, u = r >> 5, c2 = r & 31;            \
            ((unsigned int*)xb)[(t * 32 + u) * 36 + c2] = xp[base2 + (size_t)(t * V + u) * 32 + c2]; \
        }                                                                     \
    }                                                                         \
} while (0)

__global__ __launch_bounds__(256) void k_s1(
    const void* __restrict__ x,
    const unsigned short* __restrict__ wprep,
    const void* __restrict__ ba, const void* __restrict__ bb,
    float* __restrict__ S1g, const int* __restrict__ flagp) {
    int f32 = *flagp;
    int tchunk = blockIdx.x, n = blockIdx.y;
    int tid = threadIdx.x;
    int lane = tid & 63, wv = tid >> 6;
    int lm = lane & 15, kq = lane >> 4;

    __shared__ __align__(16) unsigned short xb[64 * 72];       // 9216 B
    __shared__ __align__(16) unsigned short qb[3][64 * 20];    // 7680 B
    __shared__ __align__(16) unsigned short kb_[3][64 * 20];   // 7680 B
    // total 24576 B -> 6 blocks/CU

    float rbq[3], rbk[3];
    #pragma unroll
    for (int s = 0; s < 3; s++) {
        rbq[s] = ldv(ba, s * IC + lm, f32);
        rbk[s] = ldv(bb, s * IC + lm, f32);
    }

    int mrow = wv * 16 + lm;
    int drow0 = wv * 16 + (kq << 2);
    int ur0 = ((wv >> 1) & 1) << 4;   // wave quadrant rows
    int vc0 = (wv & 1) << 4;          //               cols
    int t0 = tchunk * TCH;
    int tsel = (kq >> 1) << 5;        // E-frag: k<16 -> t0 rows, k>=16 -> t1
    int ksel = (kq & 1) << 3;

    f32x4 acc0 = {0.f,0.f,0.f,0.f}, acc1 = {0.f,0.f,0.f,0.f}, acc2 = {0.f,0.f,0.f,0.f};

    STAGE_XB(0);
    __syncthreads();

    for (int pp = 0; pp < TCH / 2; pp++) {
        short8 xa0 = *(const short8*)&xb[mrow * 72 + kq * 8];
        short8 xa1 = *(const short8*)&xb[mrow * 72 + 32 + kq * 8];
        P1_QK(0, qb[0], kb_[0]);
        P1_QK(1, qb[1], kb_[1]);
        P1_QK(2, qb[2], kb_[2]);
        __syncthreads();                 // all P1 writes visible; xb reads done
        E_ACC(acc0, qb[0], kb_[0]);
        E_ACC(acc1, qb[1], kb_[1]);
        E_ACC(acc2, qb[2], kb_[2]);
        if (pp < TCH / 2 - 1) STAGE_XB(2 * pp + 2);   // overlaps with E MFMAs
        __syncthreads();                 // xb ready; E reads done before next P1
    }

    // ---- reduce into S1 (C-layout: row = kq*4+reg, col = lm, + quadrant)
    {
        int u = ur0 + (kq << 2), v = vc0 + lm;
        float* d0 = S1g + (size_t)n * 625;
        float* d1 = S1g + ((size_t)NN + n) * 625;
        float* d2 = S1g + ((size_t)2 * NN + n) * 625;
        #pragma unroll
        for (int reg = 0; reg < 4; reg++) {
            if (u + reg < V && v < V) {
                atomicAdd(&d0[(u + reg) * 25 + v], acc0[reg]);
                atomicAdd(&d1[(u + reg) * 25 + v], acc1[reg]);
                atomicAdd(&d2[(u + reg) * 25 + v], acc2[reg]);
            }
        }
    }
}

// ---------------------------------------------------------------------------
// k_a1: in place S1 row <- A_comb + w2 * softmax(S1row / 64)   (= ac1)
// ---------------------------------------------------------------------------
__global__ void k_a1(float* __restrict__ S1g, const float* __restrict__ A_comb,
                     const void* __restrict__ wA, const int* __restrict__ flagp) {
    int f32 = *flagp;
    float w2 = ldv(wA, 2, f32);
    int sn = blockIdx.x;
    int s = sn / NN;
    int u = threadIdx.x;
    if (u >= V) return;
    float* row = S1g + (size_t)sn * V * V + u * V;
    const float* ac = A_comb + (size_t)(s * V + u) * V;
    const float scale = 1.0f / 64.0f;
    float vals[V];
    float m = -1e30f;
    for (int v = 0; v < V; v++) { vals[v] = row[v] * scale; m = fmaxf(m, vals[v]); }
    float sum = 0.f;
    for (int v = 0; v < V; v++) { vals[v] = __expf(vals[v] - m); sum += vals[v]; }
    float inv = w2 / sum;
    for (int v = 0; v < V; v++) row[v] = ac[v] + vals[v] * inv;
}

// ---------------------------------------------------------------------------
// k_main (round-9 structure, 74.4us verified): direct-global weight
// fragments, in-place qab/A_in, 2 barriers per s-iter, staged coalesced
// epilogue, dead col-pad zero loop deleted.
// ---------------------------------------------------------------------------
__global__ __launch_bounds__(256, 5) void k_main(
    const void* __restrict__ x,
    const void* __restrict__ ba, const void* __restrict__ bb,
    const void* __restrict__ bd,
    const void* __restrict__ gamma, const void* __restrict__ beta,
    const void* __restrict__ wA,
    const unsigned short* __restrict__ wprep,
    const float* __restrict__ ac1g,
    void* __restrict__ outp, const int* __restrict__ flagp) {
    int f32 = *flagp;
    int bx = blockIdx.x;
    int n = bx >> 7, tc = bx & 127;
    int t0 = tc * TB;
    int tid = threadIdx.x;
    int lane = tid & 63, wv = tid >> 6;
    int lm = lane & 15, kq = lane >> 4;

    __shared__ __align__(16) unsigned short xb[64 * 72];       // 9216 B
    __shared__ __align__(16) unsigned short qab[64 * 40];      // 5120 B (q | later A_in)
    __shared__ __align__(16) unsigned short kbb[64 * 40];      // 5120 B
    __shared__ __align__(16) unsigned short xwtb[2 * 64 * 40]; // 10240 B (later epilogue stage)
    __shared__ float gs[O], bts[O], bds[O];                    // 768 B

    // ---- stage xb (bf16, rows t*32+u, stride 72)
    if (f32) {
        const float4* xp = (const float4*)x + (size_t)(n * TT + t0) * 400;
        for (int w = tid; w < 800; w += 256) {
            int t = w / 400, r = w % 400, u = r >> 4, c4 = r & 15;
            float4 v = xp[w];
            unsigned short h[4] = {f2bf(v.x), f2bf(v.y), f2bf(v.z), f2bf(v.w)};
            *(uint2*)&xb[(t * 32 + u) * 72 + c4 * 4] = *(uint2*)h;
        }
    } else {
        const unsigned int* xp = (const unsigned int*)x;
        size_t base2 = (size_t)(n * TT + t0) * V * C / 2;
        for (int w = tid; w < 1600; w += 256) {
            int t = w / 800, r = w % 800, u = r >> 5, c2 = r & 31;
            ((unsigned int*)xb)[(t * 32 + u) * 36 + c2] = xp[base2 + (size_t)(t * V + u) * 32 + c2];
        }
    }
    // zero ghost rows u=25..31 (both t)
    for (int w = tid; w < 14 * 36; w += 256) {
        int idx = w / 36, word = w % 36;
        int row = (idx < 7) ? (25 + idx) : (32 + 25 + idx - 7);
        ((unsigned int*)xb)[row * 36 + word] = 0;
    }
    // zero qab/kbb k-pad cols 16..31 (kbb: permanent; qab: refreshed by P4)
    for (int w = tid; w < 512; w += 256) {
        int r = w >> 3, cw = 8 + (w & 7);
        ((unsigned int*)qab)[r * 20 + cw] = 0;
        ((unsigned int*)kbb)[r * 20 + cw] = 0;
    }
    if (tid < O) {
        bds[tid] = ldv(bd, tid, f32) + ldv(bd, O + tid, f32) + ldv(bd, 2 * O + tid, f32);
        gs[tid] = ldv(gamma, tid, f32) * rsqrtf(1.f + 1e-5f);
        bts[tid] = ldv(beta, tid, f32);
    }
    float w3 = ldv(wA, 3, f32);

    f32x4 acc[4];
    #pragma unroll
    for (int nt = 0; nt < 4; nt++) acc[nt] = (f32x4){0.f, 0.f, 0.f, 0.f};

    int t_ = wv >> 1;
    int mrow = wv * 16 + lm;
    int drow0 = wv * 16 + (kq << 2);
    int ub = ((wv & 1) << 4) + (kq << 2);

    __syncthreads();   // xb / pads / gs ready

    // x fragments are loop-invariant: hoist
    short8 xa0 = *(const short8*)&xb[mrow * 72 + kq * 8];
    short8 xa1 = *(const short8*)&xb[mrow * 72 + 32 + kq * 8];

    for (int s = 0; s < S; s++) {
        const unsigned short* watg = wprep + s * 6912;
        const unsigned short* wbtg = watg + 1152;
        const unsigned short* wdtg = watg + 2304;
        const float* acn = ac1g + ((size_t)s * NN + n) * 625;

        // ---- P1: qa/kb MFMA (weights direct from L2-hot global)
        {
            short8 wa0 = *(const short8*)&watg[lm * 72 + kq * 8];
            short8 wa1 = *(const short8*)&watg[lm * 72 + 32 + kq * 8];
            short8 wb0 = *(const short8*)&wbtg[lm * 72 + kq * 8];
            short8 wb1 = *(const short8*)&wbtg[lm * 72 + 32 + kq * 8];
            float bq_c = ldv(ba, s * IC + lm, f32);
            float bk_c = ldv(bb, s * IC + lm, f32);
            f32x4 q = __builtin_amdgcn_mfma_f32_16x16x32_bf16(xa0, wa0, (f32x4){0.f,0.f,0.f,0.f}, 0, 0, 0);
            q = __builtin_amdgcn_mfma_f32_16x16x32_bf16(xa1, wa1, q, 0, 0, 0);
            f32x4 k = __builtin_amdgcn_mfma_f32_16x16x32_bf16(xa0, wb0, (f32x4){0.f,0.f,0.f,0.f}, 0, 0, 0);
            k = __builtin_amdgcn_mfma_f32_16x16x32_bf16(xa1, wb1, k, 0, 0, 0);
            #pragma unroll
            for (int reg = 0; reg < 4; reg++) {
                qab[(drow0 + reg) * 40 + lm] = f2bf(q[reg] + bq_c);
                kbb[(drow0 + reg) * 40 + lm] = f2bf(k[reg] + bk_c);
            }
        }
        // ---- P3: xw = xb * Wd -> xwtb transposed [t][o][v]
        {
            #pragma unroll
            for (int nt = 0; nt < 4; nt++) {
                short8 wd0 = *(const short8*)&wdtg[(nt * 16 + lm) * 72 + kq * 8];
                short8 wd1 = *(const short8*)&wdtg[(nt * 16 + lm) * 72 + 32 + kq * 8];
                f32x4 xw = __builtin_amdgcn_mfma_f32_16x16x32_bf16(xa0, wd0, (f32x4){0.f,0.f,0.f,0.f}, 0, 0, 0);
                xw = __builtin_amdgcn_mfma_f32_16x16x32_bf16(xa1, wd1, xw, 0, 0, 0);
                unsigned short h[4] = {f2bf(xw[0]), f2bf(xw[1]), f2bf(xw[2]), f2bf(xw[3])};
                *(uint2*)&xwtb[t_ * 2560 + (nt * 16 + lm) * 40 + ub] = *(uint2*)h;
            }
        }
        __syncthreads();   // sync_A: kbb (P1->P2, cross-wave), xwtb (P3->P4, cross-wave)

        // ---- P2: E MFMA -> exp -> rowsum(shfl) -> combine -> A_in (into qab, in place)
        {
            short8 aq = *(const short8*)&qab[mrow * 40 + kq * 8];
            short8 bk0 = *(const short8*)&kbb[(t_ * 32 + lm) * 40 + kq * 8];
            short8 bk1 = *(const short8*)&kbb[(t_ * 32 + 16 + lm) * 40 + kq * 8];
            f32x4 e0 = __builtin_amdgcn_mfma_f32_16x16x32_bf16(aq, bk0, (f32x4){0.f,0.f,0.f,0.f}, 0, 0, 0);
            f32x4 e1 = __builtin_amdgcn_mfma_f32_16x16x32_bf16(aq, bk1, (f32x4){0.f,0.f,0.f,0.f}, 0, 0, 0);
            #pragma unroll
            for (int reg = 0; reg < 4; reg++) {
                float p0 = __expf(e0[reg] * 0.25f);
                float p1 = (lm < V - 16) ? __expf(e1[reg] * 0.25f) : 0.f;
                float pr = p0 + p1;
                pr += __shfl_xor(pr, 1);
                pr += __shfl_xor(pr, 2);
                pr += __shfl_xor(pr, 4);
                pr += __shfl_xor(pr, 8);
                float si = w3 / pr;
                int u = ub + reg;
                int uc = (u < V) ? u : 0;
                float a0v = (u < V) ? (acn[uc * 25 + lm] + si * p0) : 0.f;
                float a1v = (u < V && lm < V - 16) ? (acn[uc * 25 + 16 + lm] + si * p1) : 0.f;
                qab[(drow0 + reg) * 40 + lm] = f2bf(a0v);
                qab[(drow0 + reg) * 40 + 16 + lm] = f2bf(a1v);
            }
        }
        // ---- P4: y += A_in * xwtb  (no barrier needed: qab rows wave-private,
        //      xwtb written pre-sync_A)
        {
            short8 aA = *(const short8*)&qab[mrow * 40 + kq * 8];
            #pragma unroll
            for (int nt = 0; nt < 4; nt++) {
                short8 bx8 = *(const short8*)&xwtb[t_ * 2560 + (nt * 16 + lm) * 40 + kq * 8];
                acc[nt] = __builtin_amdgcn_mfma_f32_16x16x32_bf16(aA, bx8, acc[nt], 0, 0, 0);
            }
            // restore qab K-pad zeros for next s's aq read (wave-private rows)
            if (s < S - 1) {
                #pragma unroll
                for (int reg = 0; reg < 4; reg++)
                    qab[(drow0 + reg) * 40 + 16 + lm] = 0;
            }
        }
        __syncthreads();   // sync_B: next-iter P1/P3 overwrite kbb/xwtb
    }

    // ---- epilogue: BN + residual + relu
    if (f32) {
        #pragma unroll
        for (int nt = 0; nt < 4; nt++) {
            int o = nt * 16 + lm;
            float g = gs[o], bt_ = bts[o], bsum = bds[o];
            #pragma unroll
            for (int reg = 0; reg < 4; reg++) {
                int grow = drow0 + reg;
                int t = grow >> 5, u = grow & 31;
                if (u < V) {
                    float xres = b2f(*(const bf16*)&xb[grow * 72 + o]);
                    float yv = fmaxf((acc[nt][reg] + bsum) * g + bt_ + xres, 0.f);
                    size_t ob = (size_t)((n * TT + t0 + t) * V + u) * O + o;
                    ((float*)outp)[ob] = yv;
                }
            }
        }
    } else {
        // stage bf16 results in xwtb (free after last P4 + sync_B), then dump
        // the block's contiguous 6400B output with coalesced 16B stores.
        unsigned short* ep = xwtb;
        #pragma unroll
        for (int nt = 0; nt < 4; nt++) {
            int o = nt * 16 + lm;
            float g = gs[o], bt_ = bts[o], bsum = bds[o];
            #pragma unroll
            for (int reg = 0; reg < 4; reg++) {
                int grow = drow0 + reg;
                int t = grow >> 5, u = grow & 31;
                if (u < V) {
                    float xres = b2f(*(const bf16*)&xb[grow * 72 + o]);
                    float yv = fmaxf((acc[nt][reg] + bsum) * g + bt_ + xres, 0.f);
                    ep[(t * V + u) * O + o] = f2bf(yv);
                }
            }
        }
        __syncthreads();
        uint4* outv = (uint4*)((bf16*)outp + (size_t)(n * TT + t0) * V * O);
        const uint4* epv = (const uint4*)ep;
        for (int w = tid; w < 400; w += 256) outv[w] = epv[w];
    }
}

// ---------------------------------------------------------------------------
extern "C" void kernel_launch(void* const* d_in, const int* in_sizes, int n_in,
                              void* d_out, int out_size, void* d_ws, size_t ws_size,
                              hipStream_t stream) {
    const void* x     = d_in[0];
    const void* A     = d_in[1];
    const void* PA    = d_in[2];
    const void* wA    = d_in[3];
    const void* Wa    = d_in[4];
    const void* ba    = d_in[5];
    const void* Wb    = d_in[6];
    const void* bb    = d_in[7];
    const void* Wd    = d_in[8];
    const void* bd    = d_in[9];
    const void* gamma = d_in[10];
    const void* beta  = d_in[11];

    int*   flagp  = (int*)d_ws;
    float* wsf    = (float*)d_ws;
    float* A_comb = wsf + 64;                         // 1875 f
    float* S1     = wsf + 2048;                       // 60000 f (becomes ac1)
    unsigned short* wprep = (unsigned short*)(wsf + 65536);  // 20736 sh

    k_prep<<<256, 256, 0, stream>>>(x, A, PA, wA, Wa, Wb, Wd, A_comb, S1, wprep, flagp);
    k_s1<<<dim3(TT / TCH, NN), 256, 0, stream>>>(x, wprep, ba, bb, S1, flagp);
    k_a1<<<S * NN, 64, 0, stream>>>(S1, A_comb, wA, flagp);
    k_main<<<NN * TT / TB, 256, 0, stream>>>(x, ba, bb, bd, gamma, beta, wA,
                                             wprep, S1, d_out, flagp);
}

// Round 11
// 190.664 us; speedup vs baseline: 1.1990x; 1.1144x over previous
//
#include <hip/hip_runtime.h>
#include <hip/hip_bf16.h>

typedef __hip_bfloat16 bf16;
typedef __attribute__((ext_vector_type(8))) short short8;
typedef __attribute__((ext_vector_type(4))) float f32x4;

#define S  3
#define V  25
#define C  64
#define O  64
#define IC 16
#define NN 32
#define TT 256
#define TB 4
#define TCH 8

__device__ __forceinline__ float b2f(bf16 v) { return __bfloat162float(v); }

__device__ __forceinline__ float ldv(const void* p, size_t i, int f32) {
    return f32 ? ((const float*)p)[i] : b2f(((const bf16*)p)[i]);
}

__device__ __forceinline__ unsigned short f2bf(float f) {
    bf16 h = __float2bfloat16(f);
    return *(unsigned short*)&h;
}

// ---------------------------------------------------------------------------
// k_prep: dtype sniff; zero S1; weights -> bf16 MFMA layouts; A_comb.
// ---------------------------------------------------------------------------
__global__ __launch_bounds__(256) void k_prep(
    const void* __restrict__ x,
    const void* __restrict__ A, const void* __restrict__ PA,
    const void* __restrict__ wA,
    const void* __restrict__ Wa, const void* __restrict__ Wb,
    const void* __restrict__ Wd,
    float* __restrict__ A_comb, float* __restrict__ S1,
    unsigned short* __restrict__ wprep, int* __restrict__ flagp) {
    __shared__ int sflag;
    if (threadIdx.x < 64) {
        const bf16* p = (const bf16*)x;
        int bad = 0;
        #pragma unroll
        for (int k = 0; k < 32; k++) {
            float v = b2f(p[threadIdx.x + k * 64]);
            bad |= !(v > -1000.f && v < 1000.f);
        }
        unsigned long long m = __ballot(bad);
        if (threadIdx.x == 0) {
            sflag = (m != 0ull) ? 1 : 0;
            if (blockIdx.x == 0) *flagp = sflag;
        }
    }
    __syncthreads();
    int f32 = sflag;

    int g = blockIdx.x * 256 + threadIdx.x;
    int stride = gridDim.x * 256;

    for (int w = g; w < 60000; w += stride) S1[w] = 0.f;

    for (int w = g; w < 3456; w += stride) {           // Wa/Wb -> [i][c] bf16
        int s = w / 1152, r = w % 1152, i = r / 72, c = r % 72;
        unsigned short va = 0, vb = 0;
        if (c < 64) {
            va = f2bf(ldv(Wa, (size_t)s * 1024 + c * 16 + i, f32));
            vb = f2bf(ldv(Wb, (size_t)s * 1024 + c * 16 + i, f32));
        }
        wprep[s * 6912 + i * 72 + c] = va;
        wprep[s * 6912 + 1152 + i * 72 + c] = vb;
    }
    for (int w = g; w < 13824; w += stride) {          // Wd -> [o][c] bf16
        int s = w / 4608, r = w % 4608, o = r / 72, c = r % 72;
        unsigned short vd = 0;
        if (c < 64) vd = f2bf(ldv(Wd, (size_t)s * 4096 + c * 64 + o, f32));
        wprep[s * 6912 + 2304 + o * 72 + c] = vd;
    }

    if (g < S * V) {                                    // A_comb rows
        float w0 = ldv(wA, 0, f32), w1 = ldv(wA, 1, f32);
        float vals[V];
        float m = -1e30f;
        for (int v = 0; v < V; v++) { vals[v] = ldv(PA, g * V + v, f32); m = fmaxf(m, vals[v]); }
        float sum = 0.f;
        for (int v = 0; v < V; v++) { vals[v] = __expf(vals[v] - m); sum += vals[v]; }
        float inv = 1.f / sum;
        for (int v = 0; v < V; v++)
            A_comb[g * V + v] = w0 * ldv(A, g * V + v, f32) + w1 * vals[v] * inv;
    }
}

// ---------------------------------------------------------------------------
// k_s1 (round-8/10 exact, best-measured): TCH=8, grid 1024 blocks, 6/CU;
// 2 barriers per t-pair; weights direct from L2-hot wprep.
// ---------------------------------------------------------------------------
#define P1_QK(sidx, QB, KB) do {                                              \
    const unsigned short* wat_ = wprep + (size_t)(sidx) * 6912;               \
    const unsigned short* wbt_ = wat_ + 1152;                                 \
    short8 wa0 = *(const short8*)&wat_[lm * 72 + kq * 8];                     \
    short8 wa1 = *(const short8*)&wat_[lm * 72 + 32 + kq * 8];                \
    short8 wb0 = *(const short8*)&wbt_[lm * 72 + kq * 8];                     \
    short8 wb1 = *(const short8*)&wbt_[lm * 72 + 32 + kq * 8];                \
    f32x4 q = __builtin_amdgcn_mfma_f32_16x16x32_bf16(xa0, wa0, (f32x4){0.f,0.f,0.f,0.f}, 0, 0, 0); \
    q = __builtin_amdgcn_mfma_f32_16x16x32_bf16(xa1, wa1, q, 0, 0, 0);        \
    f32x4 k = __builtin_amdgcn_mfma_f32_16x16x32_bf16(xa0, wb0, (f32x4){0.f,0.f,0.f,0.f}, 0, 0, 0); \
    k = __builtin_amdgcn_mfma_f32_16x16x32_bf16(xa1, wb1, k, 0, 0, 0);        \
    _Pragma("unroll")                                                         \
    for (int reg = 0; reg < 4; reg++) {                                       \
        (QB)[(drow0 + reg) * 20 + lm] = f2bf(q[reg] + rbq[sidx]);             \
        (KB)[(drow0 + reg) * 20 + lm] = f2bf(k[reg] + rbk[sidx]);             \
    }                                                                         \
} while (0)

#define E_ACC(AC, QB, KB) do {                                                \
    short8 a_ = *(const short8*)&(QB)[(tsel + ur0 + lm) * 20 + ksel];         \
    short8 b_ = *(const short8*)&(KB)[(tsel + vc0 + lm) * 20 + ksel];         \
    (AC) = __builtin_amdgcn_mfma_f32_16x16x32_bf16(a_, b_, (AC), 0, 0, 0);    \
} while (0)

#define STAGE_XB(TTOFF) do {                                                  \
    if (f32) {                                                                \
        const float4* xp = (const float4*)x + (size_t)(n * TT + t0 + (TTOFF)) * 400; \
        for (int w = tid; w < 800; w += 256) {                                \
            int t = w / 400, r = w % 400, u = r >> 4, c4 = r & 15;            \
            float4 v = xp[w];                                                 \
            unsigned short h[4] = {f2bf(v.x), f2bf(v.y), f2bf(v.z), f2bf(v.w)}; \
            *(uint2*)&xb[(t * 32 + u) * 72 + c4 * 4] = *(uint2*)h;            \
        }                                                                     \
    } else {                                                                  \
        const unsigned int* xp = (const unsigned int*)x;                      \
        size_t base2 = (size_t)(n * TT + t0 + (TTOFF)) * V * C / 2;           \
        for (int w = tid; w < 1600; w += 256) {                               \
            int t = w / 800, r = w % 800, u = r >> 5, c2 = r & 31;            \
            ((unsigned int*)xb)[(t * 32 + u) * 36 + c2] = xp[base2 + (size_t)(t * V + u) * 32 + c2]; \
        }                                                                     \
    }                                                                         \
} while (0)

__global__ __launch_bounds__(256) void k_s1(
    const void* __restrict__ x,
    const unsigned short* __restrict__ wprep,
    const void* __restrict__ ba, const void* __restrict__ bb,
    float* __restrict__ S1g, const int* __restrict__ flagp) {
    int f32 = *flagp;
    int tchunk = blockIdx.x, n = blockIdx.y;
    int tid = threadIdx.x;
    int lane = tid & 63, wv = tid >> 6;
    int lm = lane & 15, kq = lane >> 4;

    __shared__ __align__(16) unsigned short xb[64 * 72];       // 9216 B
    __shared__ __align__(16) unsigned short qb[3][64 * 20];    // 7680 B
    __shared__ __align__(16) unsigned short kb_[3][64 * 20];   // 7680 B

    float rbq[3], rbk[3];
    #pragma unroll
    for (int s = 0; s < 3; s++) {
        rbq[s] = ldv(ba, s * IC + lm, f32);
        rbk[s] = ldv(bb, s * IC + lm, f32);
    }

    int mrow = wv * 16 + lm;
    int drow0 = wv * 16 + (kq << 2);
    int ur0 = ((wv >> 1) & 1) << 4;
    int vc0 = (wv & 1) << 4;
    int t0 = tchunk * TCH;
    int tsel = (kq >> 1) << 5;
    int ksel = (kq & 1) << 3;

    f32x4 acc0 = {0.f,0.f,0.f,0.f}, acc1 = {0.f,0.f,0.f,0.f}, acc2 = {0.f,0.f,0.f,0.f};

    STAGE_XB(0);
    __syncthreads();

    for (int pp = 0; pp < TCH / 2; pp++) {
        short8 xa0 = *(const short8*)&xb[mrow * 72 + kq * 8];
        short8 xa1 = *(const short8*)&xb[mrow * 72 + 32 + kq * 8];
        P1_QK(0, qb[0], kb_[0]);
        P1_QK(1, qb[1], kb_[1]);
        P1_QK(2, qb[2], kb_[2]);
        __syncthreads();
        E_ACC(acc0, qb[0], kb_[0]);
        E_ACC(acc1, qb[1], kb_[1]);
        E_ACC(acc2, qb[2], kb_[2]);
        if (pp < TCH / 2 - 1) STAGE_XB(2 * pp + 2);
        __syncthreads();
    }

    {
        int u = ur0 + (kq << 2), v = vc0 + lm;
        float* d0 = S1g + (size_t)n * 625;
        float* d1 = S1g + ((size_t)NN + n) * 625;
        float* d2 = S1g + ((size_t)2 * NN + n) * 625;
        #pragma unroll
        for (int reg = 0; reg < 4; reg++) {
            if (u + reg < V && v < V) {
                atomicAdd(&d0[(u + reg) * 25 + v], acc0[reg]);
                atomicAdd(&d1[(u + reg) * 25 + v], acc1[reg]);
                atomicAdd(&d2[(u + reg) * 25 + v], acc2[reg]);
            }
        }
    }
}

// ---------------------------------------------------------------------------
// k_a1: in place S1 row <- A_comb + w2 * softmax(S1row / 64)   (= ac1)
// ---------------------------------------------------------------------------
__global__ void k_a1(float* __restrict__ S1g, const float* __restrict__ A_comb,
                     const void* __restrict__ wA, const int* __restrict__ flagp) {
    int f32 = *flagp;
    float w2 = ldv(wA, 2, f32);
    int sn = blockIdx.x;
    int s = sn / NN;
    int u = threadIdx.x;
    if (u >= V) return;
    float* row = S1g + (size_t)sn * V * V + u * V;
    const float* ac = A_comb + (size_t)(s * V + u) * V;
    const float scale = 1.0f / 64.0f;
    float vals[V];
    float m = -1e30f;
    for (int v = 0; v < V; v++) { vals[v] = row[v] * scale; m = fmaxf(m, vals[v]); }
    float sum = 0.f;
    for (int v = 0; v < V; v++) { vals[v] = __expf(vals[v] - m); sum += vals[v]; }
    float inv = w2 / sum;
    for (int v = 0; v < V; v++) row[v] = ac[v] + vals[v] * inv;
}

// ---------------------------------------------------------------------------
// k_main round-11: TB=4, ONE WAVE = ONE TIMESTEP. All P1/P2/P3/P4 deps are
// wave-private (qa/kb/A_in rows, per-wave xw scratch, acc) -> ZERO barriers
// in the s-loop (same-wave LDS ordering via compiler lgkmcnt, same mechanism
// as the verified in-place-qab trick). Kernel barriers: 3 (was 8).
// P3 fused with P4 per-nt through a 1.25KB/wave scratch (xwtb 10240->2560B).
// LDS pool 44032 B -> 3 blocks/CU, 12 waves. acn L2 reads hoisted above E.
// ---------------------------------------------------------------------------
#define SM_HALF(EA, EB, UH) do {                                              \
    _Pragma("unroll")                                                         \
    for (int reg = 0; reg < 4; reg++) {                                       \
        float p0 = __expf((EA)[reg] * 0.25f);                                 \
        float p1 = (lm < V - 16) ? __expf((EB)[reg] * 0.25f) : 0.f;           \
        float pr = p0 + p1;                                                   \
        pr += __shfl_xor(pr, 1);                                              \
        pr += __shfl_xor(pr, 2);                                              \
        pr += __shfl_xor(pr, 4);                                              \
        pr += __shfl_xor(pr, 8);                                              \
        float si = w3 / pr;                                                   \
        int u = (UH) * 16 + (kq << 2) + reg;                                  \
        float a0v = (u < V) ? (pa0[UH][reg] + si * p0) : 0.f;                 \
        float a1v = (u < V && lm < V - 16) ? (pa1[UH][reg] + si * p1) : 0.f;  \
        qab[(wv * 32 + (UH) * 16 + (kq << 2) + reg) * 40 + lm] = f2bf(a0v);   \
        qab[(wv * 32 + (UH) * 16 + (kq << 2) + reg) * 40 + 16 + lm] = f2bf(a1v); \
    }                                                                         \
} while (0)

__global__ __launch_bounds__(256, 3) void k_main(
    const void* __restrict__ x,
    const void* __restrict__ ba, const void* __restrict__ bb,
    const void* __restrict__ bd,
    const void* __restrict__ gamma, const void* __restrict__ beta,
    const void* __restrict__ wA,
    const unsigned short* __restrict__ wprep,
    const float* __restrict__ ac1g,
    void* __restrict__ outp, const int* __restrict__ flagp) {
    int f32 = *flagp;
    int bx = blockIdx.x;
    int n = bx >> 6, tc = bx & 63;
    int t0 = tc * TB;
    int tid = threadIdx.x;
    int lane = tid & 63, wv = tid >> 6;    // wave wv owns timestep t0+wv
    int lm = lane & 15, kq = lane >> 4;

    __shared__ __align__(16) unsigned short pool[22016];   // 44032 B
    unsigned short* xb  = pool;            // [128][72] sh = 9216 sh
    unsigned short* qab = pool + 9216;     // [128][40] sh = 5120 sh (q | A_in)
    unsigned short* kbb = pool + 14336;    // [128][40] sh = 5120 sh
    unsigned short* xws = pool + 19456 + wv * 640;  // per-wave [16][40] sh

    // ---- stage xb (bf16, rows t*32+u, stride 72, 4 timesteps)
    if (f32) {
        const float4* xp = (const float4*)x + (size_t)(n * TT + t0) * 400;
        for (int w = tid; w < 1600; w += 256) {
            int t = w / 400, r = w % 400, u = r >> 4, c4 = r & 15;
            float4 v = xp[w];
            unsigned short h[4] = {f2bf(v.x), f2bf(v.y), f2bf(v.z), f2bf(v.w)};
            *(uint2*)&xb[(t * 32 + u) * 72 + c4 * 4] = *(uint2*)h;
        }
    } else {
        const unsigned int* xp = (const unsigned int*)x;
        size_t base2 = (size_t)(n * TT + t0) * V * C / 2;
        for (int w = tid; w < 3200; w += 256) {
            int t = w / 800, r = w % 800, u = r >> 5, c2 = r & 31;
            ((unsigned int*)xb)[(t * 32 + u) * 36 + c2] = xp[base2 + (size_t)(t * V + u) * 32 + c2];
        }
    }
    // zero ghost rows u=25..31 (4 timesteps)
    for (int w = tid; w < 28 * 36; w += 256) {
        int idx = w / 36, word = w % 36;
        int t = idx / 7, ur = 25 + idx % 7;
        ((unsigned int*)xb)[(t * 32 + ur) * 36 + word] = 0;
    }
    // zero qab/kbb k-pad cols 16..31 (128 rows; qab pads refreshed after P4)
    for (int w = tid; w < 1024; w += 256) {
        int r = w >> 3, cw = 8 + (w & 7);
        ((unsigned int*)qab)[r * 20 + cw] = 0;
        ((unsigned int*)kbb)[r * 20 + cw] = 0;
    }
    float w3 = ldv(wA, 3, f32);

    f32x4 acc0[4], acc1[4];
    #pragma unroll
    for (int nt = 0; nt < 4; nt++) {
        acc0[nt] = (f32x4){0.f, 0.f, 0.f, 0.f};
        acc1[nt] = (f32x4){0.f, 0.f, 0.f, 0.f};
    }

    __syncthreads();   // barrier 1: xb / pads ready

    // x fragments (loop-invariant): uh-half × K-half
    short8 xa00 = *(const short8*)&xb[(wv * 32 + lm) * 72 + kq * 8];
    short8 xa01 = *(const short8*)&xb[(wv * 32 + lm) * 72 + 32 + kq * 8];
    short8 xa10 = *(const short8*)&xb[(wv * 32 + 16 + lm) * 72 + kq * 8];
    short8 xa11 = *(const short8*)&xb[(wv * 32 + 16 + lm) * 72 + 32 + kq * 8];

    for (int s = 0; s < S; s++) {
        const unsigned short* watg = wprep + s * 6912;
        const unsigned short* wbtg = watg + 1152;
        const unsigned short* wdtg = watg + 2304;
        const float* acn = ac1g + ((size_t)s * NN + n) * 625;
        float bq_c = ldv(ba, s * IC + lm, f32);
        float bk_c = ldv(bb, s * IC + lm, f32);

        // ---- P1: qa/kb for both u-halves of this wave's timestep
        {
            short8 wa0 = *(const short8*)&watg[lm * 72 + kq * 8];
            short8 wa1 = *(const short8*)&watg[lm * 72 + 32 + kq * 8];
            short8 wb0 = *(const short8*)&wbtg[lm * 72 + kq * 8];
            short8 wb1 = *(const short8*)&wbtg[lm * 72 + 32 + kq * 8];
            f32x4 q0 = __builtin_amdgcn_mfma_f32_16x16x32_bf16(xa00, wa0, (f32x4){0.f,0.f,0.f,0.f}, 0, 0, 0);
            q0 = __builtin_amdgcn_mfma_f32_16x16x32_bf16(xa01, wa1, q0, 0, 0, 0);
            f32x4 q1 = __builtin_amdgcn_mfma_f32_16x16x32_bf16(xa10, wa0, (f32x4){0.f,0.f,0.f,0.f}, 0, 0, 0);
            q1 = __builtin_amdgcn_mfma_f32_16x16x32_bf16(xa11, wa1, q1, 0, 0, 0);
            f32x4 k0 = __builtin_amdgcn_mfma_f32_16x16x32_bf16(xa00, wb0, (f32x4){0.f,0.f,0.f,0.f}, 0, 0, 0);
            k0 = __builtin_amdgcn_mfma_f32_16x16x32_bf16(xa01, wb1, k0, 0, 0, 0);
            f32x4 k1 = __builtin_amdgcn_mfma_f32_16x16x32_bf16(xa10, wb0, (f32x4){0.f,0.f,0.f,0.f}, 0, 0, 0);
            k1 = __builtin_amdgcn_mfma_f32_16x16x32_bf16(xa11, wb1, k1, 0, 0, 0);
            int r0 = wv * 32 + (kq << 2);
            #pragma unroll
            for (int reg = 0; reg < 4; reg++) {
                qab[(r0 + reg) * 40 + lm]      = f2bf(q0[reg] + bq_c);
                qab[(r0 + 16 + reg) * 40 + lm] = f2bf(q1[reg] + bq_c);
                kbb[(r0 + reg) * 40 + lm]      = f2bf(k0[reg] + bk_c);
                kbb[(r0 + 16 + reg) * 40 + lm] = f2bf(k1[reg] + bk_c);
            }
        }

        // ---- hoisted ac1 row loads (independent of E; hide L2 latency)
        float pa0[2][4], pa1[2][4];
        #pragma unroll
        for (int uh = 0; uh < 2; uh++)
            #pragma unroll
            for (int reg = 0; reg < 4; reg++) {
                int u = uh * 16 + (kq << 2) + reg;
                int uc = (u < V) ? u : 0;
                pa0[uh][reg] = acn[uc * 25 + lm];
                pa1[uh][reg] = (lm < V - 16) ? acn[uc * 25 + 16 + lm] : 0.f;
            }

        // ---- P2: E MFMA (wave-private rows) -> softmax -> A_in in-place
        {
            short8 aq0 = *(const short8*)&qab[(wv * 32 + lm) * 40 + kq * 8];
            short8 aq1 = *(const short8*)&qab[(wv * 32 + 16 + lm) * 40 + kq * 8];
            short8 bk0 = *(const short8*)&kbb[(wv * 32 + lm) * 40 + kq * 8];
            short8 bk1 = *(const short8*)&kbb[(wv * 32 + 16 + lm) * 40 + kq * 8];
            f32x4 e00 = __builtin_amdgcn_mfma_f32_16x16x32_bf16(aq0, bk0, (f32x4){0.f,0.f,0.f,0.f}, 0, 0, 0);
            f32x4 e01 = __builtin_amdgcn_mfma_f32_16x16x32_bf16(aq0, bk1, (f32x4){0.f,0.f,0.f,0.f}, 0, 0, 0);
            f32x4 e10 = __builtin_amdgcn_mfma_f32_16x16x32_bf16(aq1, bk0, (f32x4){0.f,0.f,0.f,0.f}, 0, 0, 0);
            f32x4 e11 = __builtin_amdgcn_mfma_f32_16x16x32_bf16(aq1, bk1, (f32x4){0.f,0.f,0.f,0.f}, 0, 0, 0);
            SM_HALF(e00, e01, 0);
            SM_HALF(e10, e11, 1);
        }

        // ---- P3+P4 fused per nt through per-wave scratch (no barriers)
        {
            short8 aA0 = *(const short8*)&qab[(wv * 32 + lm) * 40 + kq * 8];
            short8 aA1 = *(const short8*)&qab[(wv * 32 + 16 + lm) * 40 + kq * 8];
            #pragma unroll
            for (int nt = 0; nt < 4; nt++) {
                short8 wd0 = *(const short8*)&wdtg[(nt * 16 + lm) * 72 + kq * 8];
                short8 wd1 = *(const short8*)&wdtg[(nt * 16 + lm) * 72 + 32 + kq * 8];
                f32x4 xw0 = __builtin_amdgcn_mfma_f32_16x16x32_bf16(xa00, wd0, (f32x4){0.f,0.f,0.f,0.f}, 0, 0, 0);
                xw0 = __builtin_amdgcn_mfma_f32_16x16x32_bf16(xa01, wd1, xw0, 0, 0, 0);
                f32x4 xw1 = __builtin_amdgcn_mfma_f32_16x16x32_bf16(xa10, wd0, (f32x4){0.f,0.f,0.f,0.f}, 0, 0, 0);
                xw1 = __builtin_amdgcn_mfma_f32_16x16x32_bf16(xa11, wd1, xw1, 0, 0, 0);
                unsigned short h0[4] = {f2bf(xw0[0]), f2bf(xw0[1]), f2bf(xw0[2]), f2bf(xw0[3])};
                unsigned short h1[4] = {f2bf(xw1[0]), f2bf(xw1[1]), f2bf(xw1[2]), f2bf(xw1[3])};
                *(uint2*)&xws[lm * 40 + (kq << 2)]      = *(uint2*)h0;
                *(uint2*)&xws[lm * 40 + 16 + (kq << 2)] = *(uint2*)h1;
                short8 bx8 = *(const short8*)&xws[lm * 40 + kq * 8];
                acc0[nt] = __builtin_amdgcn_mfma_f32_16x16x32_bf16(aA0, bx8, acc0[nt], 0, 0, 0);
                acc1[nt] = __builtin_amdgcn_mfma_f32_16x16x32_bf16(aA1, bx8, acc1[nt], 0, 0, 0);
            }
        }
        // restore qab K-pad zeros for next s (wave-private rows)
        if (s < S - 1) {
            #pragma unroll
            for (int reg = 0; reg < 4; reg++) {
                qab[(wv * 32 + (kq << 2) + reg) * 40 + 16 + lm] = 0;
                qab[(wv * 32 + 16 + (kq << 2) + reg) * 40 + 16 + lm] = 0;
            }
        }
    }

    __syncthreads();   // barrier 2: all waves done before pool reuse / stores

    // ---- epilogue: BN + residual + relu (biases direct from L2-hot global)
    if (f32) {
        #pragma unroll
        for (int nt = 0; nt < 4; nt++) {
            int o = nt * 16 + lm;
            float g = ldv(gamma, o, 1) * rsqrtf(1.f + 1e-5f);
            float bt_ = ldv(beta, o, 1);
            float bsum = ldv(bd, o, 1) + ldv(bd, O + o, 1) + ldv(bd, 2 * O + o, 1);
            #pragma unroll
            for (int uh = 0; uh < 2; uh++)
                #pragma unroll
                for (int reg = 0; reg < 4; reg++) {
                    int u = uh * 16 + (kq << 2) + reg;
                    if (u < V) {
                        float av = uh ? acc1[nt][reg] : acc0[nt][reg];
                        float xres = b2f(*(const bf16*)&xb[(wv * 32 + u) * 72 + o]);
                        float yv = fmaxf((av + bsum) * g + bt_ + xres, 0.f);
                        size_t ob = (size_t)((n * TT + t0 + wv) * V + u) * O + o;
                        ((float*)outp)[ob] = yv;
                    }
                }
        }
    } else {
        // stage bf16 results (pool reuse @qab, 6400 sh, wave-disjoint rows)
        unsigned short* ep = pool + 9216;
        #pragma unroll
        for (int nt = 0; nt < 4; nt++) {
            int o = nt * 16 + lm;
            float g = ldv(gamma, o, 0) * rsqrtf(1.f + 1e-5f);
            float bt_ = ldv(beta, o, 0);
            float bsum = ldv(bd, o, 0) + ldv(bd, O + o, 0) + ldv(bd, 2 * O + o, 0);
            #pragma unroll
            for (int uh = 0; uh < 2; uh++)
                #pragma unroll
                for (int reg = 0; reg < 4; reg++) {
                    int u = uh * 16 + (kq << 2) + reg;
                    if (u < V) {
                        float av = uh ? acc1[nt][reg] : acc0[nt][reg];
                        float xres = b2f(*(const bf16*)&xb[(wv * 32 + u) * 72 + o]);
                        float yv = fmaxf((av + bsum) * g + bt_ + xres, 0.f);
                        ep[(wv * V + u) * O + o] = f2bf(yv);
                    }
                }
        }
        __syncthreads();   // barrier 3
        uint4* outv = (uint4*)((bf16*)outp + (size_t)(n * TT + t0) * V * O);
        const uint4* epv = (const uint4*)ep;
        for (int w = tid; w < 800; w += 256) outv[w] = epv[w];
    }
}

// ---------------------------------------------------------------------------
extern "C" void kernel_launch(void* const* d_in, const int* in_sizes, int n_in,
                              void* d_out, int out_size, void* d_ws, size_t ws_size,
                              hipStream_t stream) {
    const void* x     = d_in[0];
    const void* A     = d_in[1];
    const void* PA    = d_in[2];
    const void* wA    = d_in[3];
    const void* Wa    = d_in[4];
    const void* ba    = d_in[5];
    const void* Wb    = d_in[6];
    const void* bb    = d_in[7];
    const void* Wd    = d_in[8];
    const void* bd    = d_in[9];
    const void* gamma = d_in[10];
    const void* beta  = d_in[11];

    int*   flagp  = (int*)d_ws;
    float* wsf    = (float*)d_ws;
    float* A_comb = wsf + 64;                         // 1875 f
    float* S1     = wsf + 2048;                       // 60000 f (becomes ac1)
    unsigned short* wprep = (unsigned short*)(wsf + 65536);  // 20736 sh

    k_prep<<<256, 256, 0, stream>>>(x, A, PA, wA, Wa, Wb, Wd, A_comb, S1, wprep, flagp);
    k_s1<<<dim3(TT / TCH, NN), 256, 0, stream>>>(x, wprep, ba, bb, S1, flagp);
    k_a1<<<S * NN, 64, 0, stream>>>(S1, A_comb, wA, flagp);
    k_main<<<NN * TT / TB, 256, 0, stream>>>(x, ba, bb, bd, gamma, beta, wA,
                                             wprep, S1, d_out, flagp);
}